// Round 1
// baseline (243.276 us; speedup 1.0000x reference)
//
#include <hip/hip_runtime.h>
#include <stdint.h>

#define E_TOTAL 1000000
#define FD      128
#define ETILE   64
#define NTILES  (E_TOTAL / ETILE)   // 15625 exactly
#define GRID    1024

typedef __attribute__((ext_vector_type(8))) short short8;
typedef __attribute__((ext_vector_type(4))) short short4v;
typedef __attribute__((ext_vector_type(4))) float f32x4;

// round-to-nearest-even fp32 -> bf16 (bit pattern in a short)
__device__ __forceinline__ short f2bf(float f) {
  union { float f; unsigned u; } v; v.f = f;
  unsigned r = (v.u + 0x7FFFu + ((v.u >> 16) & 1u)) >> 16;
  return (short)(r & 0xFFFFu);
}

__global__ __launch_bounds__(256, 2)
void linkpred_kernel(const float* __restrict__ x,
                     const int* __restrict__ ei,       // [2][E_TOTAL], int32
                     const float* __restrict__ W1, const float* __restrict__ b1,
                     const float* __restrict__ A1,
                     const float* __restrict__ W2, const float* __restrict__ b2,
                     const float* __restrict__ A2,
                     const float* __restrict__ W3, const float* __restrict__ b3,
                     const float* __restrict__ A3,
                     const float* __restrict__ Wf, const float* __restrict__ bfp,
                     float* __restrict__ out)
{
  // padded strides: row byte-stride keeps quad-lane b128 reads at 2-way (free) aliasing
  __shared__ __align__(16) short H0[ETILE][264];  // concat(x[src],x[dst]) bf16, 33792 B
  __shared__ __align__(16) short H1[ETILE][72];   // 9216 B
  __shared__ __align__(16) short H2[ETILE][40];   // 5120 B
  __shared__ float H3[ETILE][17];                 // 4352 B
  __shared__ int   SIDX[2][ETILE];                // 512 B

  const int tid  = threadIdx.x;
  const int w    = tid >> 6;     // wave 0..3
  const int lane = tid & 63;
  const int col  = lane & 15;
  const int quad = lane >> 4;    // 0..3

  // ---------------- register-resident weight B-fragments ----------------
  // Layer1: Wcat1 = [W1 | A1] (K=256, N=128). Wave w owns cols {16w..} and {64+16w..}.
  short8 B1f[2][8];
  for (int p = 0; p < 2; ++p) {
    const int n = 16 * (w + 4 * p) + col;                     // 0..127
    const float* src = (p == 0) ? (W1 + n) : (A1 + (n - 64)); // col within its half
    for (int kt = 0; kt < 8; ++kt) {
      short8 f;
      for (int j = 0; j < 8; ++j)
        f[j] = f2bf(src[(kt * 32 + quad * 8 + j) * 64]);
      B1f[p][kt] = f;
    }
  }
  // Layer2: Wcat2 = [W2 | A2] (K=64, N=64). Wave w owns col pair {16*(w&1), 32+16*(w&1)}.
  short8 B2f[2][2];
  for (int p = 0; p < 2; ++p) {
    const int n = 16 * ((w & 1) + 2 * p) + col;               // 0..63
    const float* src = (p == 0) ? (W2 + n) : (A2 + (n - 32));
    for (int kt = 0; kt < 2; ++kt) {
      short8 f;
      for (int j = 0; j < 8; ++j)
        f[j] = f2bf(src[(kt * 32 + quad * 8 + j) * 32]);
      B2f[p][kt] = f;
    }
  }
  // Layer3: Wcat3 = [W3 | A3] (K=32, N=32). All waves own col pair {0,16}.
  short8 B3f[2];
  for (int p = 0; p < 2; ++p) {
    const int n = 16 * p + col;                               // 0..31
    const float* src = (p == 0) ? (W3 + n) : (A3 + (n - 16));
    short8 f;
    for (int j = 0; j < 8; ++j)
      f[j] = f2bf(src[(quad * 8 + j) * 16]);
    B3f[p] = f;
  }
  const float b1v = b1[16 * w + col];
  const float b2v = b2[16 * (w & 1) + col];
  const float b3v = b3[col];
  const float bfv = bfp[0];
  const f32x4 zero = {0.f, 0.f, 0.f, 0.f};

  for (int tile = blockIdx.x; tile < NTILES; tile += gridDim.x) {
    const int e0 = tile * ETILE;

    // ---- stage edge indices ----
    if (tid < ETILE)            SIDX[0][tid] = ei[e0 + tid];
    else if (tid < 2 * ETILE)   SIDX[1][tid - ETILE] = ei[E_TOTAL + e0 + (tid - ETILE)];
    __syncthreads();

    // ---- gather: each wave fills one edge-row per iteration (coalesced 512B runs) ----
    for (int it = 0; it < ETILE / 4; ++it) {
      const int e    = it * 4 + w;
      const int node = SIDX[lane >> 5][e];     // lanes 0..31: src, 32..63: dst
      const int cc   = lane & 31;              // float4 index within the 128-float row
      float4 v = ((const float4*)(x + (size_t)node * FD))[cc];
      short4v s;
      s[0] = f2bf(v.x); s[1] = f2bf(v.y); s[2] = f2bf(v.z); s[3] = f2bf(v.w);
      *(short4v*)&H0[e][lane * 4] = s;
    }
    __syncthreads();

    // ---- layer 1: [64x256] @ [256x128], wave w -> all M, col pair {w, w+4} ----
    f32x4 acc[4][2];
    for (int mt = 0; mt < 4; ++mt) { acc[mt][0] = zero; acc[mt][1] = zero; }
    for (int kt = 0; kt < 8; ++kt) {
      for (int mt = 0; mt < 4; ++mt) {
        short8 a = *(const short8*)&H0[mt * 16 + col][kt * 32 + quad * 8];
        acc[mt][0] = __builtin_amdgcn_mfma_f32_16x16x32_bf16(a, B1f[0][kt], acc[mt][0], 0, 0, 0);
        acc[mt][1] = __builtin_amdgcn_mfma_f32_16x16x32_bf16(a, B1f[1][kt], acc[mt][1], 0, 0, 0);
      }
    }
    for (int mt = 0; mt < 4; ++mt)
      for (int r = 0; r < 4; ++r) {
        float o = fmaxf(acc[mt][0][r] + b1v, 0.f);        // relu(h@W1 + b1)
        float h = fmaxf(o + acc[mt][1][r], 0.f);          // relu(out + h@A1)
        H1[mt * 16 + quad * 4 + r][16 * w + col] = f2bf(h);
      }
    __syncthreads();

    // ---- layer 2: [64x64] @ [64x64], waves split M in halves, col pair {w&1, (w&1)+2} ----
    f32x4 acc2[2][2];
    acc2[0][0] = zero; acc2[0][1] = zero; acc2[1][0] = zero; acc2[1][1] = zero;
    for (int kt = 0; kt < 2; ++kt)
      for (int mi = 0; mi < 2; ++mi) {
        const int m = (2 * (w >> 1) + mi) * 16 + col;
        short8 a = *(const short8*)&H1[m][kt * 32 + quad * 8];
        acc2[mi][0] = __builtin_amdgcn_mfma_f32_16x16x32_bf16(a, B2f[0][kt], acc2[mi][0], 0, 0, 0);
        acc2[mi][1] = __builtin_amdgcn_mfma_f32_16x16x32_bf16(a, B2f[1][kt], acc2[mi][1], 0, 0, 0);
      }
    for (int mi = 0; mi < 2; ++mi)
      for (int r = 0; r < 4; ++r) {
        float o = fmaxf(acc2[mi][0][r] + b2v, 0.f);
        float h = fmaxf(o + acc2[mi][1][r], 0.f);
        H2[(2 * (w >> 1) + mi) * 16 + quad * 4 + r][16 * (w & 1) + col] = f2bf(h);
      }
    __syncthreads();

    // ---- layer 3: [64x32] @ [32x32], wave w -> M-tile w, col pair {0,1} ----
    f32x4 acc3[2];
    acc3[0] = zero; acc3[1] = zero;
    {
      short8 a = *(const short8*)&H2[w * 16 + col][quad * 8];
      acc3[0] = __builtin_amdgcn_mfma_f32_16x16x32_bf16(a, B3f[0], acc3[0], 0, 0, 0);
      acc3[1] = __builtin_amdgcn_mfma_f32_16x16x32_bf16(a, B3f[1], acc3[1], 0, 0, 0);
    }
    for (int r = 0; r < 4; ++r) {
      float o = fmaxf(acc3[0][r] + b3v, 0.f);
      float h = fmaxf(o + acc3[1][r], 0.f);
      H3[w * 16 + quad * 4 + r][col] = h;
    }
    __syncthreads();

    // ---- final: 16-dot + sigmoid in fp32, one thread per edge ----
    if (tid < ETILE) {
      float s = bfv;
      for (int j = 0; j < 16; ++j) s += H3[tid][j] * Wf[j];
      out[e0 + tid] = 1.0f / (1.0f + __expf(-s));
    }
    // no trailing barrier needed: next-iteration writes (SIDX) don't alias H3,
    // and H0/H1/H2/H3 writes all sit behind at least one __syncthreads.
  }
}

extern "C" void kernel_launch(void* const* d_in, const int* in_sizes, int n_in,
                              void* d_out, int out_size, void* d_ws, size_t ws_size,
                              hipStream_t stream) {
  const float* x   = (const float*)d_in[0];
  const int*   ei  = (const int*)d_in[1];
  const float* W1  = (const float*)d_in[2];
  const float* b1  = (const float*)d_in[3];
  const float* A1  = (const float*)d_in[4];
  const float* W2  = (const float*)d_in[5];
  const float* b2  = (const float*)d_in[6];
  const float* A2  = (const float*)d_in[7];
  const float* W3  = (const float*)d_in[8];
  const float* b3  = (const float*)d_in[9];
  const float* A3  = (const float*)d_in[10];
  const float* Wf  = (const float*)d_in[11];
  const float* bfp = (const float*)d_in[12];

  hipLaunchKernelGGL(linkpred_kernel, dim3(GRID), dim3(256), 0, stream,
                     x, ei, W1, b1, A1, W2, b2, A2, W3, b3, A3, Wf, bfp,
                     (float*)d_out);
}